// Round 16
// baseline (271.238 us; speedup 1.0000x reference)
//
#include <hip/hip_runtime.h>
#include <hip/hip_fp16.h>

#define NN 50000
#define NE 800000
#define DIM 128
#define NB ((NN + 255) / 256)   // 196 scan chunks
#define N4 (NN * DIM / 4)       // 1.6M cvt work items
#define APAD 8                  // As row stride 136 halfs = 272B (16B aligned, 2-way banks)

typedef _Float16 half8 __attribute__((ext_vector_type(8)));
typedef float f32x4 __attribute__((ext_vector_type(4)));

// ================= CSR build =================
__global__ __launch_bounds__(256) void edge_histo_pos(const int* __restrict__ ei,
                                                      int* __restrict__ cnt,
                                                      int* __restrict__ pos) {
  int e = blockIdx.x * 256 + threadIdx.x;
  if (e >= NE) return;
  int r = ei[e], c = ei[NE + e];
  int p = -1;
  if ((unsigned)r < NN && (unsigned)c < NN) p = atomicAdd(&cnt[r], 1);
  pos[e] = p;
}

__global__ __launch_bounds__(256) void block_sums(const int* __restrict__ cnt,
                                                  int* __restrict__ bsum) {
  int i = blockIdx.x * 256 + threadIdx.x;
  int v = (i < NN) ? cnt[i] : 0;
#pragma unroll
  for (int off = 1; off < 64; off <<= 1) v += __shfl_xor(v, off, 64);
  __shared__ int ws[4];
  if ((threadIdx.x & 63) == 0) ws[threadIdx.x >> 6] = v;
  __syncthreads();
  if (threadIdx.x == 0) bsum[blockIdx.x] = ws[0] + ws[1] + ws[2] + ws[3];
}

// scan_final2: per-block redundant reduce of bsum[0..bid) for base, then local scan.
__global__ __launch_bounds__(256) void scan_final2(const int* __restrict__ cnt,
                                                   const int* __restrict__ bsum,
                                                   int* __restrict__ rowStart) {
  const int t = threadIdx.x, bid = blockIdx.x;
  // base = sum of bsum[0..bid-1]
  int s = (t < bid && t < NB) ? bsum[t] : 0;
#pragma unroll
  for (int off = 1; off < 64; off <<= 1) s += __shfl_xor(s, off, 64);
  __shared__ int wsum[4];
  if ((t & 63) == 0) wsum[t >> 6] = s;
  __syncthreads();
  const int base = wsum[0] + wsum[1] + wsum[2] + wsum[3];

  int i = bid * 256 + t;
  int v = (i < NN) ? cnt[i] : 0;
  int lane = t & 63, w = t >> 6;
  int inc = v;
#pragma unroll
  for (int off = 1; off < 64; off <<= 1) {
    int u = __shfl_up(inc, off, 64);
    if (lane >= off) inc += u;
  }
  __shared__ int ws[4];
  if (lane == 63) ws[w] = inc;
  __syncthreads();
  int wb = 0;
  for (int k = 0; k < w; ++k) wb += ws[k];
  int ex = base + wb + inc - v;
  if (i < NN) rowStart[i] = ex;
  if (i == NN - 1) rowStart[NN] = ex + v;
}

__global__ __launch_bounds__(256) void edge_scatter(const int* __restrict__ ei,
                                                    const float* __restrict__ vals,
                                                    const int* __restrict__ rowStart,
                                                    const int* __restrict__ pos,
                                                    int2* __restrict__ cv) {
  int e = blockIdx.x * 256 + threadIdx.x;
  if (e >= NE) return;
  int p = pos[e];
  if (p < 0) return;
  int r = ei[e], c = ei[NE + e];
  cv[rowStart[r] + p] = make_int2(c, __float_as_int(vals[e]));
}

// ---- prep: x->fp16 + pack all 3 weights (fragment-major fp16) in one kernel ----
__device__ __forceinline__ void pack_one(const float* __restrict__ W,
                                         __half* __restrict__ Wp, int N, int idx) {
  int j = idx & 7, lane = (idx >> 3) & 63, ctkt = idx >> 9;
  int NC = N / 16;
  int kt = ctkt / NC, ct = ctkt - kt * NC;
  int k = kt * 32 + ((lane >> 4) << 3) + j;
  int n = ct * 16 + (lane & 15);
  Wp[idx] = __float2half(W[k * N + n]);
}

__global__ __launch_bounds__(256) void prep(const float* __restrict__ x,
                                            const float* __restrict__ W1,
                                            const float* __restrict__ W2,
                                            const float* __restrict__ W3,
                                            __half* __restrict__ x16,
                                            __half* __restrict__ Wp1,
                                            __half* __restrict__ Wp2,
                                            __half* __restrict__ Wp3) {
  int idx = blockIdx.x * 256 + threadIdx.x;
  if (idx < N4) {
    float4 v = ((const float4*)x)[idx];
    __half2 lo = __floats2half2_rn(v.x, v.y);
    __half2 hi = __floats2half2_rn(v.z, v.w);
    uint2 u;
    u.x = *(unsigned int*)&lo;
    u.y = *(unsigned int*)&hi;
    ((uint2*)x16)[idx] = u;
    return;
  }
  int k = idx - N4;
  if (k < 16384) { pack_one(W1, Wp1, 128, k); return; }
  k -= 16384;
  if (k < 16384) { pack_one(W2, Wp2, 128, k); return; }
  k -= 16384;
  if (k < 8192) pack_one(W3, Wp3, 64, k);
}

// ============ shared helpers ============
__device__ __forceinline__ void fma4(float v, const float4& x, float4& acc) {
  acc.x = fmaf(v, x.x, acc.x);
  acc.y = fmaf(v, x.y, acc.y);
  acc.z = fmaf(v, x.z, acc.z);
  acc.w = fmaf(v, x.w, acc.w);
}

__device__ __forceinline__ float4 cvt4(uint2 raw) {
  __half2 a = *reinterpret_cast<__half2*>(&raw.x);
  __half2 b = *reinterpret_cast<__half2*>(&raw.y);
  float2 fa = __half22float2(a), fb = __half22float2(b);
  return make_float4(fa.x, fa.y, fb.x, fb.y);
}

// ===== fused layer (L1/L2): gather C@h into LDS (fp16), then MFMA @W (+relu+norm) =====
// 64-row tile; 8 half-waves gather 8 rows each; MFMA phase = 4 waves x 16 rows.
template <bool FIRST>   // unused tag, layers identical
__global__ __launch_bounds__(256) void fused_spmm_gemm(const int* __restrict__ rowStart,
                                                       const int2* __restrict__ cv,
                                                       const __half* __restrict__ h,
                                                       const __half* __restrict__ Wp,
                                                       const float* __restrict__ b,
                                                       __half* __restrict__ out, int n) {
  constexpr int NC = DIM / 16;   // 8 col-tiles
  constexpr int KT = DIM / 32;   // 4 k-steps
  __shared__ __half Ws[KT * NC * 64 * 8];     // 32 KB
  __shared__ __half As[64 * (DIM + APAD)];    // 17.4 KB
  const int tid = threadIdx.x;
  for (int i = tid; i < KT * NC * 64; i += 256)
    ((half8*)Ws)[i] = ((const half8*)Wp)[i];

  const int hw = tid >> 5, lane32 = tid & 31;
  const int wid = tid >> 6, lane = tid & 63;
  const int colbase = lane & 15, kgrp = lane >> 4;
  const int ntiles = (n + 63) >> 6;

  for (int tile = blockIdx.x; tile < ntiles; tile += gridDim.x) {
    // ---- gather phase: half-wave hw -> rows hw*8 .. hw*8+7 of the tile ----
#pragma unroll
    for (int rr = 0; rr < 8; ++rr) {
      const int lrow = hw * 8 + rr;
      const int row = tile * 64 + lrow;
      float4 acc = make_float4(0.f, 0.f, 0.f, 0.f);
      if (row < n) {
        int p = rowStart[row], pend = rowStart[row + 1];
        for (; p + 3 < pend; p += 4) {
          int2 e0 = cv[p], e1 = cv[p + 1], e2 = cv[p + 2], e3 = cv[p + 3];
          uint2 r0 = ((const uint2*)(h + (size_t)e0.x * DIM))[lane32];
          uint2 r1 = ((const uint2*)(h + (size_t)e1.x * DIM))[lane32];
          uint2 r2 = ((const uint2*)(h + (size_t)e2.x * DIM))[lane32];
          uint2 r3 = ((const uint2*)(h + (size_t)e3.x * DIM))[lane32];
          fma4(__int_as_float(e0.y), cvt4(r0), acc);
          fma4(__int_as_float(e1.y), cvt4(r1), acc);
          fma4(__int_as_float(e2.y), cvt4(r2), acc);
          fma4(__int_as_float(e3.y), cvt4(r3), acc);
        }
        for (; p < pend; ++p) {
          int2 e0 = cv[p];
          uint2 r0 = ((const uint2*)(h + (size_t)e0.x * DIM))[lane32];
          fma4(__int_as_float(e0.y), cvt4(r0), acc);
        }
      }
      __half2 lo = __floats2half2_rn(acc.x, acc.y);
      __half2 hi = __floats2half2_rn(acc.z, acc.w);
      uint2 u;
      u.x = *(unsigned int*)&lo;
      u.y = *(unsigned int*)&hi;
      *(uint2*)(As + lrow * (DIM + APAD) + lane32 * 4) = u;   // 8B ds_write
    }
    __syncthreads();   // As (+Ws first iter) visible

    // ---- MFMA phase ----
    f32x4 acc2[NC];
#pragma unroll
    for (int ct = 0; ct < NC; ++ct) {
      float bv = b[ct * 16 + colbase];
      acc2[ct] = (f32x4){bv, bv, bv, bv};
    }
#pragma unroll
    for (int kt = 0; kt < KT; ++kt) {
      half8 af = *(const half8*)(As + (wid * 16 + colbase) * (DIM + APAD) + kt * 32 + kgrp * 8);
#pragma unroll
      for (int ct = 0; ct < NC; ++ct) {
        half8 bf = ((const half8*)Ws)[(kt * NC + ct) * 64 + lane];
        acc2[ct] = __builtin_amdgcn_mfma_f32_16x16x32_f16(af, bf, acc2[ct], 0, 0, 0);
      }
    }
    const int row0 = tile * 64 + wid * 16;
#pragma unroll
    for (int j = 0; j < 4; ++j) {
      int row = row0 + (kgrp << 2) + j;
      float s = 0.f;
#pragma unroll
      for (int ct = 0; ct < NC; ++ct) {
        float v = fmaxf(acc2[ct][j], 0.f);
        s = fmaf(v, v, s);
      }
      s += __shfl_xor(s, 1); s += __shfl_xor(s, 2);
      s += __shfl_xor(s, 4); s += __shfl_xor(s, 8);
      float inv = 1.0f / fmaxf(sqrtf(s), 1e-12f);
      if (row < n) {
#pragma unroll
        for (int ct = 0; ct < NC; ++ct)
          out[(size_t)row * DIM + ct * 16 + colbase] =
              __float2half(fmaxf(acc2[ct][j], 0.f) * inv);
      }
    }
    __syncthreads();   // epilogue reads done before next tile's gather overwrites As
  }
}

// ============ standalone MFMA GEMM for layer 3 (g = hh @ W3, fp16 out) ============
template <int NOUT>
__global__ __launch_bounds__(256) void gemm_mfma(const __half* __restrict__ A,
                                                 const __half* __restrict__ Wp,
                                                 __half* __restrict__ out, int n) {
  constexpr int NC = NOUT / 16;
  constexpr int KT = DIM / 32;
  __shared__ __half Ws[KT * NC * 64 * 8];
  const int tid = threadIdx.x;
  for (int i = tid; i < KT * NC * 64; i += 256)
    ((half8*)Ws)[i] = ((const half8*)Wp)[i];
  __syncthreads();

  const int wid = tid >> 6, lane = tid & 63;
  const int colbase = lane & 15, kgrp = lane >> 4;
  const int ntiles = (n + 63) >> 6;

  for (int tile = blockIdx.x; tile < ntiles; tile += gridDim.x) {
    const int row0 = tile * 64 + wid * 16;
    int rowA = row0 + colbase;
    if (rowA > n - 1) rowA = n - 1;
    const half8* Arow = (const half8*)(A + (size_t)rowA * DIM);
    f32x4 acc[NC];
#pragma unroll
    for (int ct = 0; ct < NC; ++ct) acc[ct] = (f32x4){0.f, 0.f, 0.f, 0.f};
#pragma unroll
    for (int kt = 0; kt < KT; ++kt) {
      half8 af = Arow[kt * 4 + kgrp];
#pragma unroll
      for (int ct = 0; ct < NC; ++ct) {
        half8 bf = ((const half8*)Ws)[(kt * NC + ct) * 64 + lane];
        acc[ct] = __builtin_amdgcn_mfma_f32_16x16x32_f16(af, bf, acc[ct], 0, 0, 0);
      }
    }
#pragma unroll
    for (int j = 0; j < 4; ++j) {
      int row = row0 + (kgrp << 2) + j;
      if (row < n) {
#pragma unroll
        for (int ct = 0; ct < NC; ++ct)
          out[(size_t)row * NOUT + ct * 16 + colbase] = __float2half(acc[ct][j]);
      }
    }
  }
}

// ============ SpMM gather (fp16 src), fp32 out + bias — final layer ============
template <int D>
__global__ __launch_bounds__(256) void spmm_csr_f(const int* __restrict__ rowStart,
                                                  const int2* __restrict__ cv,
                                                  const __half* __restrict__ h,
                                                  const float* __restrict__ bias,
                                                  float* __restrict__ out) {
  constexpr int L = D / 4;
  const int lane = threadIdx.x % L;
  const int r = blockIdx.x * (256 / L) + threadIdx.x / L;
  if (r >= NN) return;
  int p = rowStart[r], pend = rowStart[r + 1];
  float4 acc = ((const float4*)bias)[lane];
  for (; p + 3 < pend; p += 4) {
    int2 e0 = cv[p], e1 = cv[p + 1], e2 = cv[p + 2], e3 = cv[p + 3];
    uint2 r0 = ((const uint2*)(h + (size_t)e0.x * D))[lane];
    uint2 r1 = ((const uint2*)(h + (size_t)e1.x * D))[lane];
    uint2 r2 = ((const uint2*)(h + (size_t)e2.x * D))[lane];
    uint2 r3 = ((const uint2*)(h + (size_t)e3.x * D))[lane];
    fma4(__int_as_float(e0.y), cvt4(r0), acc);
    fma4(__int_as_float(e1.y), cvt4(r1), acc);
    fma4(__int_as_float(e2.y), cvt4(r2), acc);
    fma4(__int_as_float(e3.y), cvt4(r3), acc);
  }
  for (; p < pend; ++p) {
    int2 e0 = cv[p];
    uint2 r0 = ((const uint2*)(h + (size_t)e0.x * D))[lane];
    fma4(__int_as_float(e0.y), cvt4(r0), acc);
  }
  ((float4*)(out + (size_t)r * D))[lane] = acc;
}

// ---------------- fallback: fp32 atomic path (if ws too small) ----------------
__global__ __launch_bounds__(256) void spmm_atomic(
    const int* __restrict__ ei, const float* __restrict__ vals,
    const float* __restrict__ h, float* __restrict__ prop) {
  const int lane32 = threadIdx.x & 31;
  int hw = blockIdx.x * (blockDim.x >> 5) + (threadIdx.x >> 5);
  const int stride = gridDim.x * (blockDim.x >> 5);
  for (int e = hw; e < NE; e += stride) {
    int r = ei[e], c = ei[NE + e];
    float v = vals[e];
    if ((unsigned)r >= NN || (unsigned)c >= NN) continue;
    float4 x = ((const float4*)(h + (size_t)c * DIM))[lane32];
    float* pp = prop + (size_t)r * DIM + lane32 * 4;
    unsafeAtomicAdd(pp + 0, v * x.x);
    unsafeAtomicAdd(pp + 1, v * x.y);
    unsafeAtomicAdd(pp + 2, v * x.z);
    unsafeAtomicAdd(pp + 3, v * x.w);
  }
}

template <int OUT_DIM, int MR, bool NORM>
__global__ __launch_bounds__(256) void gemm_fb(
    const float* __restrict__ A, const float* __restrict__ W,
    const float* __restrict__ b, float* __restrict__ out, int n) {
  constexpr int JT = OUT_DIM / 4;
  constexpr int RG = 256 / JT;
  constexpr int TILE_M = RG * MR;
  const int j = threadIdx.x % JT, rg = threadIdx.x / JT;
  const int row0 = blockIdx.x * TILE_M + rg * MR;
  float4 bv = ((const float4*)b)[j];
  float acc[MR][4];
#pragma unroll
  for (int i = 0; i < MR; ++i) {
    acc[i][0] = bv.x; acc[i][1] = bv.y; acc[i][2] = bv.z; acc[i][3] = bv.w;
  }
  const float* Arow[MR];
#pragma unroll
  for (int i = 0; i < MR; ++i) {
    int r = row0 + i; if (r > n - 1) r = n - 1;
    Arow[i] = A + (size_t)r * DIM;
  }
  for (int kk = 0; kk < DIM; ++kk) {
    const float* Wr = W + (size_t)kk * OUT_DIM + j * 4;
    float4 w = *(const float4*)Wr;
#pragma unroll
    for (int i = 0; i < MR; ++i) {
      float a = Arow[i][kk];
      acc[i][0] = fmaf(a, w.x, acc[i][0]);
      acc[i][1] = fmaf(a, w.y, acc[i][1]);
      acc[i][2] = fmaf(a, w.z, acc[i][2]);
      acc[i][3] = fmaf(a, w.w, acc[i][3]);
    }
  }
#pragma unroll
  for (int i = 0; i < MR; ++i) {
    int row = row0 + i;
    float v0 = acc[i][0], v1 = acc[i][1], v2 = acc[i][2], v3 = acc[i][3];
    if (NORM) {
      v0 = fmaxf(v0, 0.f); v1 = fmaxf(v1, 0.f);
      v2 = fmaxf(v2, 0.f); v3 = fmaxf(v3, 0.f);
      float s = v0 * v0 + v1 * v1 + v2 * v2 + v3 * v3;
#pragma unroll
      for (int off = JT / 2; off >= 1; off >>= 1) s += __shfl_xor(s, off, JT);
      float inv = 1.0f / fmaxf(sqrtf(s), 1e-12f);
      v0 *= inv; v1 *= inv; v2 *= inv; v3 *= inv;
    }
    if (row < n)
      ((float4*)(out + (size_t)row * OUT_DIM))[j] = make_float4(v0, v1, v2, v3);
  }
}

extern "C" void kernel_launch(void* const* d_in, const int* in_sizes, int n_in,
                              void* d_out, int out_size, void* d_ws, size_t ws_size,
                              hipStream_t stream) {
  const float* x  = (const float*)d_in[0];
  const int*   ei = (const int*)d_in[1];
  const float* C  = (const float*)d_in[2];
  const float* W1 = (const float*)d_in[3];
  const float* b1 = (const float*)d_in[4];
  const float* W2 = (const float*)d_in[5];
  const float* b2 = (const float*)d_in[6];
  const float* W3 = (const float*)d_in[7];
  const float* b3 = (const float*)d_in[8];
  float* out = (float*)d_out;

  // ---- workspace layout ----
  __half* x16      = (__half*)d_ws;                    // NN*DIM (L2: hh16)
  __half* h16      = x16 + (size_t)NN * DIM;           // NN*DIM (L3: g16)
  __half* Wp1      = h16 + (size_t)NN * DIM;           // 16384
  __half* Wp2      = Wp1 + 16384;                      // 16384
  __half* Wp3      = Wp2 + 16384;                      // 8192
  int*    rowStart = (int*)(Wp3 + 8192);               // NN+2
  int*    cnt      = rowStart + NN + 2;                // NN
  int*    bsum     = cnt + NN;                         // 256
  int*    pos      = bsum + 256;                       // NE
  int2*   cv       = (int2*)(pos + NE);                // NE
  const size_t need = (size_t)(2 * NN * DIM) * 2 + 40960 * 2 +
                      (size_t)(2 * NN + 2 + 256) * 4 + (size_t)NE * 4 + (size_t)NE * 8;

  const dim3 blk(256);
  const int gEdge = (NE + 255) / 256;
  const int gFused = 768;              // 3 blocks/CU, grid-stride 782 tiles
  const int gTiles = (NN + 63) / 64;

  if (ws_size >= need) {
    prep<<<(N4 + 40960 + 255) / 256, blk, 0, stream>>>(x, W1, W2, W3, x16, Wp1, Wp2, Wp3);
    hipMemsetAsync(cnt, 0, (size_t)NN * 4, stream);
    edge_histo_pos<<<gEdge, blk, 0, stream>>>(ei, cnt, pos);
    block_sums<<<NB, blk, 0, stream>>>(cnt, bsum);
    scan_final2<<<NB, blk, 0, stream>>>(cnt, bsum, rowStart);
    edge_scatter<<<gEdge, blk, 0, stream>>>(ei, C, rowStart, pos, cv);

    // layer 1 fused: h16 = norm(relu((C@x16)@W1 + b1))
    fused_spmm_gemm<true><<<gFused, blk, 0, stream>>>(rowStart, cv, x16, Wp1, b1, h16, NN);
    // layer 2 fused: hh16 = norm(relu((C@h16)@W2 + b2))   (x16 buffer reused)
    __half* hh16 = x16;
    fused_spmm_gemm<false><<<gFused, blk, 0, stream>>>(rowStart, cv, h16, Wp2, b2, hh16, NN);
    // layer 3: g16 = hh16@W3; out = C@g16 + b3            (h16 buffer reused)
    __half* g16 = h16;
    gemm_mfma<64><<<gTiles, blk, 0, stream>>>(hh16, Wp3, g16, NN);
    spmm_csr_f<64><<<(NN + 15) / 16, blk, 0, stream>>>(rowStart, cv, g16, b3, out);
  } else {
    // fallback: fp32 atomic path
    float* prop = (float*)d_ws;
    float* h    = prop + (size_t)NN * DIM;
    const size_t propBytes = (size_t)NN * DIM * sizeof(float);
    hipMemsetAsync(prop, 0, propBytes, stream);
    spmm_atomic<<<4096, blk, 0, stream>>>(ei, C, x, prop);
    gemm_fb<128, 4, true><<<(NN + 31) / 32, blk, 0, stream>>>(prop, W1, b1, h, NN);
    hipMemsetAsync(prop, 0, propBytes, stream);
    spmm_atomic<<<4096, blk, 0, stream>>>(ei, C, h, prop);
    gemm_fb<128, 4, true><<<(NN + 31) / 32, blk, 0, stream>>>(prop, W2, b2, h, NN);
    hipMemsetAsync(prop, 0, propBytes, stream);
    spmm_atomic<<<4096, blk, 0, stream>>>(ei, C, h, prop);
    gemm_fb<64, 2, false><<<(NN + 31) / 32, blk, 0, stream>>>(prop, W3, b3, out, NN);
  }
}

// Round 17
// 190.161 us; speedup vs baseline: 1.4264x; 1.4264x over previous
//
#include <hip/hip_runtime.h>
#include <hip/hip_fp16.h>

#define NN 50000
#define NE 800000
#define DIM 128
#define NB ((NN + 255) / 256)   // 196 scan chunks
#define N4 (NN * DIM / 4)       // 1.6M cvt work items

typedef _Float16 half8 __attribute__((ext_vector_type(8)));
typedef float f32x4 __attribute__((ext_vector_type(4)));

// ================= CSR build =================
__global__ __launch_bounds__(256) void edge_histo_pos(const int* __restrict__ ei,
                                                      int* __restrict__ cnt,
                                                      int* __restrict__ pos) {
  int e = blockIdx.x * 256 + threadIdx.x;
  if (e >= NE) return;
  int r = ei[e], c = ei[NE + e];
  int p = -1;
  if ((unsigned)r < NN && (unsigned)c < NN) p = atomicAdd(&cnt[r], 1);
  pos[e] = p;
}

__global__ __launch_bounds__(256) void block_sums(const int* __restrict__ cnt,
                                                  int* __restrict__ bsum) {
  int i = blockIdx.x * 256 + threadIdx.x;
  int v = (i < NN) ? cnt[i] : 0;
#pragma unroll
  for (int off = 1; off < 64; off <<= 1) v += __shfl_xor(v, off, 64);
  __shared__ int ws[4];
  if ((threadIdx.x & 63) == 0) ws[threadIdx.x >> 6] = v;
  __syncthreads();
  if (threadIdx.x == 0) bsum[blockIdx.x] = ws[0] + ws[1] + ws[2] + ws[3];
}

// Per-block redundant reduce of bsum[0..bid) for base, then local scan (no mid kernel).
__global__ __launch_bounds__(256) void scan_final2(const int* __restrict__ cnt,
                                                   const int* __restrict__ bsum,
                                                   int* __restrict__ rowStart) {
  const int t = threadIdx.x, bid = blockIdx.x;
  int s = (t < bid && t < NB) ? bsum[t] : 0;
#pragma unroll
  for (int off = 1; off < 64; off <<= 1) s += __shfl_xor(s, off, 64);
  __shared__ int wsum[4];
  if ((t & 63) == 0) wsum[t >> 6] = s;
  __syncthreads();
  const int base = wsum[0] + wsum[1] + wsum[2] + wsum[3];

  int i = bid * 256 + t;
  int v = (i < NN) ? cnt[i] : 0;
  int lane = t & 63, w = t >> 6;
  int inc = v;
#pragma unroll
  for (int off = 1; off < 64; off <<= 1) {
    int u = __shfl_up(inc, off, 64);
    if (lane >= off) inc += u;
  }
  __shared__ int ws[4];
  if (lane == 63) ws[w] = inc;
  __syncthreads();
  int wb = 0;
  for (int k = 0; k < w; ++k) wb += ws[k];
  int ex = base + wb + inc - v;
  if (i < NN) rowStart[i] = ex;
  if (i == NN - 1) rowStart[NN] = ex + v;
}

__global__ __launch_bounds__(256) void edge_scatter(const int* __restrict__ ei,
                                                    const float* __restrict__ vals,
                                                    const int* __restrict__ rowStart,
                                                    const int* __restrict__ pos,
                                                    int2* __restrict__ cv) {
  int e = blockIdx.x * 256 + threadIdx.x;
  if (e >= NE) return;
  int p = pos[e];
  if (p < 0) return;
  int r = ei[e], c = ei[NE + e];
  cv[rowStart[r] + p] = make_int2(c, __float_as_int(vals[e]));
}

// ---- prep: x->fp16 + pack all 3 weights (fragment-major fp16) in one kernel ----
__device__ __forceinline__ void pack_one(const float* __restrict__ W,
                                         __half* __restrict__ Wp, int N, int idx) {
  int j = idx & 7, lane = (idx >> 3) & 63, ctkt = idx >> 9;
  int NC = N / 16;
  int kt = ctkt / NC, ct = ctkt - kt * NC;
  int k = kt * 32 + ((lane >> 4) << 3) + j;
  int n = ct * 16 + (lane & 15);
  Wp[idx] = __float2half(W[k * N + n]);
}

__global__ __launch_bounds__(256) void prep(const float* __restrict__ x,
                                            const float* __restrict__ W1,
                                            const float* __restrict__ W2,
                                            const float* __restrict__ W3,
                                            __half* __restrict__ x16,
                                            __half* __restrict__ Wp1,
                                            __half* __restrict__ Wp2,
                                            __half* __restrict__ Wp3) {
  int idx = blockIdx.x * 256 + threadIdx.x;
  if (idx < N4) {
    float4 v = ((const float4*)x)[idx];
    __half2 lo = __floats2half2_rn(v.x, v.y);
    __half2 hi = __floats2half2_rn(v.z, v.w);
    uint2 u;
    u.x = *(unsigned int*)&lo;
    u.y = *(unsigned int*)&hi;
    ((uint2*)x16)[idx] = u;
    return;
  }
  int k = idx - N4;
  if (k < 16384) { pack_one(W1, Wp1, 128, k); return; }
  k -= 16384;
  if (k < 16384) { pack_one(W2, Wp2, 128, k); return; }
  k -= 16384;
  if (k < 8192) pack_one(W3, Wp3, 64, k);
}

// ============ shared helpers ============
__device__ __forceinline__ void fma4(float v, const float4& x, float4& acc) {
  acc.x = fmaf(v, x.x, acc.x);
  acc.y = fmaf(v, x.y, acc.y);
  acc.z = fmaf(v, x.z, acc.z);
  acc.w = fmaf(v, x.w, acc.w);
}

__device__ __forceinline__ float4 cvt4(uint2 raw) {
  __half2 a = *reinterpret_cast<__half2*>(&raw.x);
  __half2 b = *reinterpret_cast<__half2*>(&raw.y);
  float2 fa = __half22float2(a), fb = __half22float2(b);
  return make_float4(fa.x, fa.y, fb.x, fb.y);
}

// ============ SpMM gather (fp16 src); fp16 or fp32 out ============
// R16 lesson: keep gathers in many small independent blocks (no barriers) —
// fused/tiled version lost 3.5x memory-level parallelism (1.0 vs 3.6 TB/s).
template <int D, bool BIAS, bool HOUT>
__global__ __launch_bounds__(256) void spmm_csr_h(const int* __restrict__ rowStart,
                                                  const int2* __restrict__ cv,
                                                  const __half* __restrict__ h,
                                                  const float* __restrict__ bias,
                                                  void* __restrict__ outv) {
  constexpr int L = D / 4;
  const int lane = threadIdx.x % L;
  const int r = blockIdx.x * (256 / L) + threadIdx.x / L;
  if (r >= NN) return;
  int p = rowStart[r], pend = rowStart[r + 1];
  float4 acc = BIAS ? ((const float4*)bias)[lane] : make_float4(0.f, 0.f, 0.f, 0.f);
  for (; p + 7 < pend; p += 8) {
    int2 e0 = cv[p],     e1 = cv[p + 1], e2 = cv[p + 2], e3 = cv[p + 3];
    int2 e4 = cv[p + 4], e5 = cv[p + 5], e6 = cv[p + 6], e7 = cv[p + 7];
    uint2 r0 = ((const uint2*)(h + (size_t)e0.x * D))[lane];
    uint2 r1 = ((const uint2*)(h + (size_t)e1.x * D))[lane];
    uint2 r2 = ((const uint2*)(h + (size_t)e2.x * D))[lane];
    uint2 r3 = ((const uint2*)(h + (size_t)e3.x * D))[lane];
    uint2 r4 = ((const uint2*)(h + (size_t)e4.x * D))[lane];
    uint2 r5 = ((const uint2*)(h + (size_t)e5.x * D))[lane];
    uint2 r6 = ((const uint2*)(h + (size_t)e6.x * D))[lane];
    uint2 r7 = ((const uint2*)(h + (size_t)e7.x * D))[lane];
    fma4(__int_as_float(e0.y), cvt4(r0), acc);
    fma4(__int_as_float(e1.y), cvt4(r1), acc);
    fma4(__int_as_float(e2.y), cvt4(r2), acc);
    fma4(__int_as_float(e3.y), cvt4(r3), acc);
    fma4(__int_as_float(e4.y), cvt4(r4), acc);
    fma4(__int_as_float(e5.y), cvt4(r5), acc);
    fma4(__int_as_float(e6.y), cvt4(r6), acc);
    fma4(__int_as_float(e7.y), cvt4(r7), acc);
  }
  for (; p < pend; ++p) {
    int2 e0 = cv[p];
    uint2 r0 = ((const uint2*)(h + (size_t)e0.x * D))[lane];
    fma4(__int_as_float(e0.y), cvt4(r0), acc);
  }
  if (HOUT) {
    __half2 lo = __floats2half2_rn(acc.x, acc.y);
    __half2 hi = __floats2half2_rn(acc.z, acc.w);
    uint2 u;
    u.x = *(unsigned int*)&lo;
    u.y = *(unsigned int*)&hi;
    ((uint2*)((__half*)outv + (size_t)r * D))[lane] = u;
  } else {
    ((float4*)((float*)outv + (size_t)r * D))[lane] = acc;
  }
}

// ============ MFMA GEMM: out16 = A16 @ Wp (+b) (+ReLU +L2 norm), fp16 out ============
// Wave = 16 rows x NOUT cols; 4 waves/block = 64-row tile. K=128 in 4 steps of 32.
// C/D layout (m89): col = lane&15, row = (lane>>4)*4 + reg.
template <int NOUT, bool NORM, bool BIAS>
__global__ __launch_bounds__(256) void gemm_mfma(const __half* __restrict__ A,
                                                 const __half* __restrict__ Wp,
                                                 const float* __restrict__ b,
                                                 __half* __restrict__ out, int n) {
  constexpr int NC = NOUT / 16;   // col-tiles (8 or 4)
  constexpr int KT = DIM / 32;    // 4
  __shared__ __half Ws[KT * NC * 64 * 8];   // 32 KB (128) / 16 KB (64)
  const int tid = threadIdx.x;
  for (int i = tid; i < KT * NC * 64; i += 256)
    ((half8*)Ws)[i] = ((const half8*)Wp)[i];
  __syncthreads();

  const int wid = tid >> 6, lane = tid & 63;
  const int colbase = lane & 15;
  const int kgrp = lane >> 4;
  const int ntiles = (n + 63) >> 6;

  for (int tile = blockIdx.x; tile < ntiles; tile += gridDim.x) {
    const int row0 = tile * 64 + wid * 16;
    int rowA = row0 + colbase;
    if (rowA > n - 1) rowA = n - 1;
    const half8* Arow = (const half8*)(A + (size_t)rowA * DIM);

    f32x4 acc[NC];
#pragma unroll
    for (int ct = 0; ct < NC; ++ct) {
      float bv = BIAS ? b[ct * 16 + colbase] : 0.f;
      acc[ct] = (f32x4){bv, bv, bv, bv};
    }

#pragma unroll
    for (int kt = 0; kt < KT; ++kt) {
      half8 af = Arow[kt * 4 + kgrp];
#pragma unroll
      for (int ct = 0; ct < NC; ++ct) {
        half8 bf = ((const half8*)Ws)[(kt * NC + ct) * 64 + lane];
        acc[ct] = __builtin_amdgcn_mfma_f32_16x16x32_f16(af, bf, acc[ct], 0, 0, 0);
      }
    }

#pragma unroll
    for (int j = 0; j < 4; ++j) {
      int row = row0 + (kgrp << 2) + j;
      if (NORM) {
        float s = 0.f;
#pragma unroll
        for (int ct = 0; ct < NC; ++ct) {
          float v = fmaxf(acc[ct][j], 0.f);
          s = fmaf(v, v, s);
        }
        s += __shfl_xor(s, 1); s += __shfl_xor(s, 2);
        s += __shfl_xor(s, 4); s += __shfl_xor(s, 8);
        float inv = 1.0f / fmaxf(sqrtf(s), 1e-12f);
        if (row < n) {
#pragma unroll
          for (int ct = 0; ct < NC; ++ct)
            out[(size_t)row * NOUT + ct * 16 + colbase] =
                __float2half(fmaxf(acc[ct][j], 0.f) * inv);
        }
      } else {
        if (row < n) {
#pragma unroll
          for (int ct = 0; ct < NC; ++ct)
            out[(size_t)row * NOUT + ct * 16 + colbase] = __float2half(acc[ct][j]);
        }
      }
    }
  }
}

// ---------------- fallback: fp32 atomic path (if ws too small) ----------------
__global__ __launch_bounds__(256) void spmm_atomic(
    const int* __restrict__ ei, const float* __restrict__ vals,
    const float* __restrict__ h, float* __restrict__ prop) {
  const int lane32 = threadIdx.x & 31;
  int hw = blockIdx.x * (blockDim.x >> 5) + (threadIdx.x >> 5);
  const int stride = gridDim.x * (blockDim.x >> 5);
  for (int e = hw; e < NE; e += stride) {
    int r = ei[e], c = ei[NE + e];
    float v = vals[e];
    if ((unsigned)r >= NN || (unsigned)c >= NN) continue;
    float4 x = ((const float4*)(h + (size_t)c * DIM))[lane32];
    float* pp = prop + (size_t)r * DIM + lane32 * 4;
    unsafeAtomicAdd(pp + 0, v * x.x);
    unsafeAtomicAdd(pp + 1, v * x.y);
    unsafeAtomicAdd(pp + 2, v * x.z);
    unsafeAtomicAdd(pp + 3, v * x.w);
  }
}

template <int OUT_DIM, int MR, bool NORM>
__global__ __launch_bounds__(256) void gemm_fb(
    const float* __restrict__ A, const float* __restrict__ W,
    const float* __restrict__ b, float* __restrict__ out, int n) {
  constexpr int JT = OUT_DIM / 4;
  constexpr int RG = 256 / JT;
  constexpr int TILE_M = RG * MR;
  const int j = threadIdx.x % JT, rg = threadIdx.x / JT;
  const int row0 = blockIdx.x * TILE_M + rg * MR;
  float4 bv = ((const float4*)b)[j];
  float acc[MR][4];
#pragma unroll
  for (int i = 0; i < MR; ++i) {
    acc[i][0] = bv.x; acc[i][1] = bv.y; acc[i][2] = bv.z; acc[i][3] = bv.w;
  }
  const float* Arow[MR];
#pragma unroll
  for (int i = 0; i < MR; ++i) {
    int r = row0 + i; if (r > n - 1) r = n - 1;
    Arow[i] = A + (size_t)r * DIM;
  }
  for (int kk = 0; kk < DIM; ++kk) {
    const float* Wr = W + (size_t)kk * OUT_DIM + j * 4;
    float4 w = *(const float4*)Wr;
#pragma unroll
    for (int i = 0; i < MR; ++i) {
      float a = Arow[i][kk];
      acc[i][0] = fmaf(a, w.x, acc[i][0]);
      acc[i][1] = fmaf(a, w.y, acc[i][1]);
      acc[i][2] = fmaf(a, w.z, acc[i][2]);
      acc[i][3] = fmaf(a, w.w, acc[i][3]);
    }
  }
#pragma unroll
  for (int i = 0; i < MR; ++i) {
    int row = row0 + i;
    float v0 = acc[i][0], v1 = acc[i][1], v2 = acc[i][2], v3 = acc[i][3];
    if (NORM) {
      v0 = fmaxf(v0, 0.f); v1 = fmaxf(v1, 0.f);
      v2 = fmaxf(v2, 0.f); v3 = fmaxf(v3, 0.f);
      float s = v0 * v0 + v1 * v1 + v2 * v2 + v3 * v3;
#pragma unroll
      for (int off = JT / 2; off >= 1; off >>= 1) s += __shfl_xor(s, off, JT);
      float inv = 1.0f / fmaxf(sqrtf(s), 1e-12f);
      v0 *= inv; v1 *= inv; v2 *= inv; v3 *= inv;
    }
    if (row < n)
      ((float4*)(out + (size_t)row * OUT_DIM))[j] = make_float4(v0, v1, v2, v3);
  }
}

extern "C" void kernel_launch(void* const* d_in, const int* in_sizes, int n_in,
                              void* d_out, int out_size, void* d_ws, size_t ws_size,
                              hipStream_t stream) {
  const float* x  = (const float*)d_in[0];
  const int*   ei = (const int*)d_in[1];
  const float* C  = (const float*)d_in[2];
  const float* W1 = (const float*)d_in[3];
  const float* b1 = (const float*)d_in[4];
  const float* W2 = (const float*)d_in[5];
  const float* b2 = (const float*)d_in[6];
  const float* W3 = (const float*)d_in[7];
  const float* b3 = (const float*)d_in[8];
  float* out = (float*)d_out;

  // ---- workspace layout (fp16 pipeline) ----
  __half* prop16   = (__half*)d_ws;                    // NN*DIM
  __half* h16      = prop16 + (size_t)NN * DIM;        // NN*DIM (later g16)
  __half* x16      = h16 + (size_t)NN * DIM;           // NN*DIM (later hh16)
  __half* Wp1      = x16 + (size_t)NN * DIM;           // 16384
  __half* Wp2      = Wp1 + 16384;                      // 16384
  __half* Wp3      = Wp2 + 16384;                      // 8192
  int*    rowStart = (int*)(Wp3 + 8192);               // NN+2
  int*    cnt      = rowStart + NN + 2;                // NN
  int*    bsum     = cnt + NN;                         // 256
  int*    pos      = bsum + 256;                       // NE
  int2*   cv       = (int2*)(pos + NE);                // NE
  const size_t need = (size_t)(3 * NN * DIM) * 2 + 40960 * 2 +
                      (size_t)(2 * NN + 2 + 256) * 4 + (size_t)NE * 4 + (size_t)NE * 8;

  const dim3 blk(256);
  const int gEdge = (NE + 255) / 256;
  const int gTiles = (NN + 63) / 64;

  if (ws_size >= need) {
    // prep (cvt + packs) and CSR build
    prep<<<(N4 + 40960 + 255) / 256, blk, 0, stream>>>(x, W1, W2, W3, x16, Wp1, Wp2, Wp3);
    hipMemsetAsync(cnt, 0, (size_t)NN * 4, stream);
    edge_histo_pos<<<gEdge, blk, 0, stream>>>(ei, cnt, pos);
    block_sums<<<NB, blk, 0, stream>>>(cnt, bsum);
    scan_final2<<<NB, blk, 0, stream>>>(cnt, bsum, rowStart);
    edge_scatter<<<gEdge, blk, 0, stream>>>(ei, C, rowStart, pos, cv);

    // layer 1: prop16 = C@x16; h16 = fp16(norm(relu(prop16@W1 + b1)))
    spmm_csr_h<128, false, true><<<(NN + 7) / 8, blk, 0, stream>>>(rowStart, cv, x16, nullptr, prop16);
    gemm_mfma<128, true, true><<<gTiles, blk, 0, stream>>>(prop16, Wp1, b1, h16, NN);
    // layer 2: prop16 = C@h16; hh16 = fp16(norm(relu(prop16@W2 + b2)))  (reuse x16)
    spmm_csr_h<128, false, true><<<(NN + 7) / 8, blk, 0, stream>>>(rowStart, cv, h16, nullptr, prop16);
    __half* hh16 = x16;
    gemm_mfma<128, true, true><<<gTiles, blk, 0, stream>>>(prop16, Wp2, b2, hh16, NN);
    // layer 3 reassociated: g16 = fp16(hh16@W3); out = C@g16 + b3  (reuse h16)
    __half* g16 = h16;
    gemm_mfma<64, false, false><<<gTiles, blk, 0, stream>>>(hh16, Wp3, nullptr, g16, NN);
    spmm_csr_h<64, true, false><<<(NN + 15) / 16, blk, 0, stream>>>(rowStart, cv, g16, b3, out);
  } else {
    // fallback: fp32 atomic path
    float* prop = (float*)d_ws;
    float* h    = prop + (size_t)NN * DIM;
    const size_t propBytes = (size_t)NN * DIM * sizeof(float);
    hipMemsetAsync(prop, 0, propBytes, stream);
    spmm_atomic<<<4096, blk, 0, stream>>>(ei, C, x, prop);
    gemm_fb<128, 4, true><<<(NN + 31) / 32, blk, 0, stream>>>(prop, W1, b1, h, NN);
    hipMemsetAsync(prop, 0, propBytes, stream);
    spmm_atomic<<<4096, blk, 0, stream>>>(ei, C, h, prop);
    gemm_fb<128, 4, true><<<(NN + 31) / 32, blk, 0, stream>>>(prop, W2, b2, h, NN);
    hipMemsetAsync(prop, 0, propBytes, stream);
    spmm_atomic<<<4096, blk, 0, stream>>>(ei, C, h, prop);
    gemm_fb<64, 2, false><<<(NN + 31) / 32, blk, 0, stream>>>(prop, W3, b3, out, NN);
  }
}